// Round 3
// baseline (371.940 us; speedup 1.0000x reference)
//
#include <hip/hip_runtime.h>

#define NB   1024
#define NL   4096
#define TPB  256
#define QSTEP 1024               // steps per block (quarter row)
#define SPT  4                   // steps per thread

// ws float-offsets
#define WS_BASE 256              // per-row: BASE[10] (L2E-prescaled), Rs at +10, stride 16
#define WS_PART 16640            // partials: [row*4+q]*12 floats
#define WS_CNT  65792            // per-row uint arrival counters (zeroed by prep)

typedef float v2f __attribute__((ext_vector_type(2)));

__device__ __forceinline__ float fast_rcp(float x) { return __builtin_amdgcn_rcpf(x); }
__device__ __forceinline__ float fexp2(float x) { return __builtin_amdgcn_exp2f(x); }  // 2^x
__device__ __forceinline__ float flog2(float x) { return __builtin_amdgcn_logf(x); }   // log2(x)

#define L2E 1.44269504088896340736f
#define LN2 0.69314718055994530942f

// Even part of softplus in log2 domain: F(x) = log2(1+2^x) - x/2 = F(-x).
// Cubic in s=x^2; max |err| ~1e-3 on |x|<=4.
#define SP_C0 1.0f
#define SP_C1 0.0864667f
#define SP_C2 (-0.0015685f)
#define SP_C3 2.5763e-5f

// ---------------- kernel A: weight prep (once) ----------------
// Keeps weights in ws so the main kernel reads them wave-uniformly
// (s_load / constant path) instead of every block redoing ~85 vector
// global loads of pW1/pW2 (R1's mistake). Also zeroes the per-row
// arrival counters used by the last-block combine.
__global__ void __launch_bounds__(256) onenet_prep(
    const float* __restrict__ X,   const float* __restrict__ SC,
    const float* __restrict__ pW1, const float* __restrict__ pb1,
    const float* __restrict__ pW2, const float* __restrict__ pb2,
    const float* __restrict__ rW1, const float* __restrict__ rb1,
    const float* __restrict__ rW2, const float* __restrict__ rb2,
    float* __restrict__ ws)
{
    const int gid = blockIdx.x * 256 + threadIdx.x;
    if (gid < NB) {
        ((unsigned*)ws)[WS_CNT + gid] = 0u;   // reset arrival counter
        float sc0 = SC[gid * 3 + 0], sc1 = SC[gid * 3 + 1], sc2 = SC[gid * 3 + 2];
        float* bp = ws + WS_BASE + gid * 16;
#pragma unroll
        for (int j = 0; j < 10; ++j) {
            float base = fmaf(sc0, pW1[20 + j],
                         fmaf(sc1, pW1[30 + j],
                         fmaf(sc2, pW1[40 + j], pb1[j])));
            bp[j] = L2E * base;
        }
        // r-net on x[:,0,:] = [SOC0, T0, sc0, sc1, sc2] (one-off: exact trans ok)
        const float* x0 = X + (size_t)gid * NL * 5;
        float T0 = x0[2], SOC0 = x0[4];
        float u = rb1[0];
        u = fmaf(SOC0, rW1[0], u);
        u = fmaf(T0,   rW1[1], u);
        u = fmaf(sc0,  rW1[2], u);
        u = fmaf(sc1,  rW1[3], u);
        u = fmaf(sc2,  rW1[4], u);
        float sp = LN2 * flog2(1.0f + fexp2(L2E * u));
        float r  = fmaf(sp, rW2[0], rb2[0]);
        bp[10] = sc2 * (1.0f + r);   // Rs
    }
    // global prescaled weights -> ws[0..74]
    if (blockIdx.x == 0 && threadIdx.x < 75) {
        const int t = threadIdx.x;
        const float LBv[5]   = {0.005f, 0.025f, 0.1f, 0.0f, 0.002f};
        const float UBLB[5]  = {0.015f, 0.045f, 0.9f, 0.055f, 0.023f};
        float v;
        if (t < 20) {
            v = L2E * pW1[t];                       // W1S rows 0..9, W1T rows 10..19
        } else if (t < 70) {
            int k = (t - 20) % 5;
            v = LN2 * 0.0025f * UBLB[k] * pW2[t - 20];   // V[j,k]
        } else {
            int k = t - 70;
            v = LBv[k] + UBLB[k] * fmaf(0.0025f, pb2[k], 0.5f);  // alpha_k
        }
        ws[t] = v;
    }
}

// ---------------- kernel B: main scan-as-reduction ----------------
// block = row*4 + q ; 256 threads x 4 steps = 1024 steps per block.
// Staging via global_load_lds width=16: LDS dest linear (wave base+lane*16),
// XOR float4 involution j^((j>>3)&7) applied on the GLOBAL source index and
// again on the LDS read side -> strided 5-float4 per-thread reads are
// bank-conflict-free (R2-verified pattern, R0/R1 occupancy geometry).
// MLP evaluated 2 steps at a time packed in v2f (v_pk_fma_f32).
// Last arriving block of each row combines the 4 quarter partials and
// writes the output directly (no final kernel).
__global__ void __launch_bounds__(TPB) onenet_main(
    const float* __restrict__ X, float* __restrict__ ws,
    float* __restrict__ out)
{
    __shared__ float4 tile[TPB * 5];          // 20 KB staging
    __shared__ float  red[TPB / 64][9];

    const int bid  = blockIdx.x;
    const int row  = bid >> 2;
    const int q    = bid & 3;
    const int tid  = threadIdx.x;
    const int lane = tid & 63;
    const int w    = tid >> 6;

    // ---- async staging: quarter-row (1024 steps, 20 KB), no VGPR trip ----
    const float* Xq = X + ((size_t)row * NL + (size_t)q * QSTEP) * 5;
#pragma unroll
    for (int k = 0; k < 5; ++k) {
        int jbase = 320 * w + 64 * k;         // wave-uniform dest float4 idx
        int j     = jbase + lane;
        int sj    = j ^ ((j >> 3) & 7);       // involution: tile[i] = g[sw(i)]
        __builtin_amdgcn_global_load_lds(
            (const __attribute__((address_space(1))) void*)(Xq + 4 * (size_t)sj),
            (__attribute__((address_space(3))) void*)&tile[jbase],
            16, 0, 0);
    }

    // ---- uniform weights (wave-uniform -> scalar loads) during DMA ----
    float W1S[10], W1T[10], BASE[10];
    float VR1[10], VRC[10], VOC[10], VMH[10], VKH[10];
#pragma unroll
    for (int j = 0; j < 10; ++j) W1S[j] = ws[j];
#pragma unroll
    for (int j = 0; j < 10; ++j) W1T[j] = ws[10 + j];
#pragma unroll
    for (int j = 0; j < 10; ++j) {
        VR1[j] = ws[20 + 5 * j + 0];
        VRC[j] = ws[20 + 5 * j + 1];
        VOC[j] = ws[20 + 5 * j + 2];
        VMH[j] = ws[20 + 5 * j + 3];
        VKH[j] = ws[20 + 5 * j + 4];
    }
    const float A0 = ws[70], A1 = ws[71], A2 = ws[72], A3 = ws[73], A4 = ws[74];
    {
        const float* bp = ws + WS_BASE + row * 16;
#pragma unroll
        for (int j = 0; j < 10; ++j) BASE[j] = bp[j];
    }

    __syncthreads();                          // staging visible

    // ---- conflict-free LDS reads: this thread's 4 steps (20 floats) ----
    float f[20];
#pragma unroll
    for (int jj = 0; jj < 5; ++jj) {
        int widx = 5 * tid + jj;
        int sw   = widx ^ ((widx >> 3) & 7);
        *(float4*)&f[4 * jj] = tile[sw];
    }
    // t of the step after this thread's last
    float tn;
    {
        int wn  = 5 * ((tid + 1) & (TPB - 1));   // clamped for tid==255
        int swn = wn ^ ((wn >> 3) & 7);
        float tl = tile[swn].x;
        if (tid < TPB - 1)      tn = tl;
        else if (q == 3)        tn = f[15];      // dt=0 -> identity at step 4095
        else                    tn = Xq[QSTEP * 5];
    }

    v2f a = {1.f, 1.f}, b = {0.f, 0.f}, cS = {0.f, 0.f}, dS = {0.f, 0.f};
    v2f oaccv = {0.f, 0.f};
    float OCV0 = 0.f, I0 = 0.f;

#pragma unroll
    for (int ip = 0; ip < 2; ++ip) {          // two step-pairs: (0,1),(2,3)
        const int i0 = 2 * ip, i1 = 2 * ip + 1;
        v2f SSv = { f[5 * i0 + 4], f[5 * i1 + 4] };
        v2f Ttv = { f[5 * i0 + 2], f[5 * i1 + 2] };
        v2f Iv  = { f[5 * i0 + 1], f[5 * i1 + 1] };
        float tnx1 = (ip == 0) ? f[5 * i1 + 5] : tn;
        v2f dtv = { f[5 * i1 + 0] - f[5 * i0 + 0], tnx1 - f[5 * i1 + 0] };
        v2f invv = { fast_rcp(Iv.x), fast_rcp(Iv.y) };

        v2f tR1 = {A0, A0}, tRC = {A1, A1}, tOC = {A2, A2},
            tMH = {A3, A3}, tKH = {A4, A4};
#pragma unroll
        for (int j = 0; j < 10; ++j) {
            v2f pre = SSv * W1S[j] + Ttv * W1T[j] + BASE[j];
            v2f s   = pre * pre;
            v2f p   = s * SP_C3 + SP_C2;
            p = s * p + SP_C1;
            p = s * p + SP_C0;
            v2f lam = pre * 0.5f + p;          // softplus2(pre), poly approx
            tR1 += lam * VR1[j];
            tRC += lam * VRC[j];
            tOC += lam * VOC[j];
            tMH += lam * VMH[j];
            tKH += lam * VKH[j];
        }
        oaccv += tOC * invv;                   // negated at the end
        if (ip == 0) { OCV0 = tOC.x; I0 = Iv.x; }

        v2f g  = dtv * tKH * Iv;
        v2f hh = dtv * tRC;
        v2f bx = g * tMH;
        v2f by = hh * tR1 * Iv;

        {   // step i0 (S-accum with pre-step U, then apply T)
            v2f sv = {1.f + g.x, 1.f - hh.x};
            v2f bv = {bx.x, by.x};
            v2f iv = {invv.x, invv.x};
            cS = iv * a + cS;
            dS = iv * b + dS;
            b  = sv * b + bv;
            a  = sv * a;
        }
        {   // step i1
            v2f sv = {1.f + g.y, 1.f - hh.y};
            v2f bv = {bx.y, by.y};
            v2f iv = {invv.y, invv.y};
            cS = iv * a + cS;
            dS = iv * b + dS;
            b  = sv * b + bv;
            a  = sv * a;
        }
    }
    float oacc = -(oaccv.x + oaccv.y);

    // wave-level order-preserving tree reduce (L=self, R=lane+off)
#pragma unroll
    for (int off = 1; off < 64; off <<= 1) {
        v2f a2, b2, c2, d2;
        a2.x = __shfl_down(a.x, off);  a2.y = __shfl_down(a.y, off);
        b2.x = __shfl_down(b.x, off);  b2.y = __shfl_down(b.y, off);
        c2.x = __shfl_down(cS.x, off); c2.y = __shfl_down(cS.y, off);
        d2.x = __shfl_down(dS.x, off); d2.y = __shfl_down(dS.y, off);
        float o2 = __shfl_down(oacc, off);
        v2f nb = a2 * b + b2;
        v2f nc = c2 * a + cS;
        v2f nd = (dS + d2) + c2 * b;
        a = a2 * a; b = nb; cS = nc; dS = nd;
        oacc += o2;
    }

    if (lane == 0) {
        red[w][0] = a.x;  red[w][1] = a.y;
        red[w][2] = b.x;  red[w][3] = b.y;
        red[w][4] = cS.x; red[w][5] = cS.y;
        red[w][6] = dS.x; red[w][7] = dS.y;
        red[w][8] = oacc;
    }
    __syncthreads();

    if (tid == 0) {
#pragma unroll
        for (int k = 1; k < TPB / 64; ++k) {
            v2f ak, bk, ck, dk;
            ak.x = red[k][0]; ak.y = red[k][1];
            bk.x = red[k][2]; bk.y = red[k][3];
            ck.x = red[k][4]; ck.y = red[k][5];
            dk.x = red[k][6]; dk.y = red[k][7];
            v2f nb = ak * b + bk;
            v2f nc = ck * a + cS;
            v2f nd = (dS + dk) + ck * b;
            a = ak * a; b = nb; cS = nc; dS = nd;
            oacc += red[k][8];
        }
        float* pw = ws + WS_PART + (size_t)bid * 12;
        pw[0] = a.x;  pw[1] = b.x;  pw[2] = cS.x; pw[3] = dS.x;
        pw[4] = a.y;  pw[5] = b.y;  pw[6] = cS.y; pw[7] = dS.y;
        pw[8] = oacc;
        if (q == 0) { pw[9] = OCV0; pw[10] = I0; }

        // ---- last-block-per-row combine (release/acquire via threadfence) ----
        __threadfence();                      // partials visible device-wide
        unsigned old = atomicAdd(((unsigned*)ws) + WS_CNT + row, 1u);
        if (old == 3u) {
            __threadfence();                  // acquire: see others' partials
            const float* p0 = ws + WS_PART + (size_t)row * 48;
            v2f A_, B_, C_, D_;
            A_.x = p0[0]; A_.y = p0[4];
            B_.x = p0[1]; B_.y = p0[5];
            C_.x = p0[2]; C_.y = p0[6];
            D_.x = p0[3]; D_.y = p0[7];
            float O = p0[8];
            float OCV00 = p0[9], I00 = p0[10];
#pragma unroll
            for (int k = 1; k < 4; ++k) {
                const float* pk = p0 + k * 12;
                v2f ak, bk, ck, dk;
                ak.x = pk[0]; ak.y = pk[4];
                bk.x = pk[1]; bk.y = pk[5];
                ck.x = pk[2]; ck.y = pk[6];
                dk.x = pk[3]; dk.y = pk[7];
                v2f nb = ak * B_ + bk;
                v2f nc = ck * A_ + C_;
                v2f nd = (D_ + dk) + ck * B_;
                A_ = ak * A_; B_ = nb; C_ = nc; D_ = nd;
                O += pk[8];
            }
            float Rs  = ws[WS_BASE + row * 16 + 10];
            float U10 = -OCV00 - I00 * Rs;        // U_H0 = 0
            float SH  = D_.x;                     // sum U_H/I
            float S1  = fmaf(C_.y, U10, D_.y);    // sum U_1/I
            out[row] = (O - SH - S1) * (1.0f / 4096.0f);
        }
    }
}

extern "C" void kernel_launch(void* const* d_in, const int* in_sizes, int n_in,
                              void* d_out, int out_size, void* d_ws, size_t ws_size,
                              hipStream_t stream) {
    const float* X   = (const float*)d_in[0];
    const float* SC  = (const float*)d_in[1];
    const float* pW1 = (const float*)d_in[2];
    const float* pb1 = (const float*)d_in[3];
    const float* pW2 = (const float*)d_in[4];
    const float* pb2 = (const float*)d_in[5];
    const float* rW1 = (const float*)d_in[6];
    const float* rb1 = (const float*)d_in[7];
    const float* rW2 = (const float*)d_in[8];
    const float* rb2 = (const float*)d_in[9];
    float* out = (float*)d_out;
    float* ws  = (float*)d_ws;

    onenet_prep<<<NB / 256, 256, 0, stream>>>(X, SC, pW1, pb1, pW2, pb2,
                                              rW1, rb1, rW2, rb2, ws);
    onenet_main<<<NB * 4, TPB, 0, stream>>>(X, ws, out);
}

// Round 4
// 141.326 us; speedup vs baseline: 2.6318x; 2.6318x over previous
//
#include <hip/hip_runtime.h>

#define NB   1024
#define NL   4096
#define TPB  256
#define QSTEP 1024               // steps per block (quarter row)
#define SPT  4                   // steps per thread

// ws float-offsets
#define WS_BASE 256              // per-row: BASE[10] (L2E-prescaled), Rs at +10, stride 16
#define WS_PART 16640            // partials: [row*4+q]*12 floats

typedef float v2f __attribute__((ext_vector_type(2)));

__device__ __forceinline__ float fast_rcp(float x) { return __builtin_amdgcn_rcpf(x); }
__device__ __forceinline__ float fexp2(float x) { return __builtin_amdgcn_exp2f(x); }  // 2^x
__device__ __forceinline__ float flog2(float x) { return __builtin_amdgcn_logf(x); }   // log2(x)

#define L2E 1.44269504088896340736f
#define LN2 0.69314718055994530942f

// Even part of softplus in log2 domain: F(x) = log2(1+2^x) - x/2 = F(-x).
// Cubic in s=x^2; max |err| ~1e-3 on |x|<=4.
#define SP_C0 1.0f
#define SP_C1 0.0864667f
#define SP_C2 (-0.0015685f)
#define SP_C3 2.5763e-5f

// ---------------- kernel A: weight prep ----------------
// NOTE (R3 lesson): no cross-block atomic/fence combine anywhere — a
// per-block __threadfence on this multi-XCD part forces L2
// writeback/invalidate and serialized the whole memory system (235 us main).
// A separate 5-us final kernel is far cheaper.
__global__ void __launch_bounds__(256) onenet_prep(
    const float* __restrict__ X,   const float* __restrict__ SC,
    const float* __restrict__ pW1, const float* __restrict__ pb1,
    const float* __restrict__ pW2, const float* __restrict__ pb2,
    const float* __restrict__ rW1, const float* __restrict__ rb1,
    const float* __restrict__ rW2, const float* __restrict__ rb2,
    float* __restrict__ ws)
{
    const int gid = blockIdx.x * 256 + threadIdx.x;
    if (gid < NB) {
        float sc0 = SC[gid * 3 + 0], sc1 = SC[gid * 3 + 1], sc2 = SC[gid * 3 + 2];
        float* bp = ws + WS_BASE + gid * 16;
#pragma unroll
        for (int j = 0; j < 10; ++j) {
            float base = fmaf(sc0, pW1[20 + j],
                         fmaf(sc1, pW1[30 + j],
                         fmaf(sc2, pW1[40 + j], pb1[j])));
            bp[j] = L2E * base;
        }
        // r-net on x[:,0,:] = [SOC0, T0, sc0, sc1, sc2] (one-off: exact trans ok)
        const float* x0 = X + (size_t)gid * NL * 5;
        float T0 = x0[2], SOC0 = x0[4];
        float u = rb1[0];
        u = fmaf(SOC0, rW1[0], u);
        u = fmaf(T0,   rW1[1], u);
        u = fmaf(sc0,  rW1[2], u);
        u = fmaf(sc1,  rW1[3], u);
        u = fmaf(sc2,  rW1[4], u);
        float sp = LN2 * flog2(1.0f + fexp2(L2E * u));
        float r  = fmaf(sp, rW2[0], rb2[0]);
        bp[10] = sc2 * (1.0f + r);   // Rs
    }
    // global prescaled weights -> ws[0..74]
    if (blockIdx.x == 0 && threadIdx.x < 75) {
        const int t = threadIdx.x;
        const float LBv[5]   = {0.005f, 0.025f, 0.1f, 0.0f, 0.002f};
        const float UBLB[5]  = {0.015f, 0.045f, 0.9f, 0.055f, 0.023f};
        float v;
        if (t < 20) {
            v = L2E * pW1[t];                       // W1S rows 0..9, W1T rows 10..19
        } else if (t < 70) {
            int k = (t - 20) % 5;
            v = LN2 * 0.0025f * UBLB[k] * pW2[t - 20];   // V[j,k]
        } else {
            int k = t - 70;
            v = LBv[k] + UBLB[k] * fmaf(0.0025f, pb2[k], 0.5f);  // alpha_k
        }
        ws[t] = v;
    }
}

// ---------------- kernel B: main scan-as-reduction ----------------
// block = row*4 + q ; 256 threads x 4 steps = 1024 steps per block.
// Staging via global_load_lds width=16 (no VGPR round trip): LDS dest is
// linear per wave (base + lane*16); the XOR float4 involution j^((j>>3)&7)
// is applied on the GLOBAL source index and again on the LDS read side ->
// strided 5-float4 per-thread reads are bank-conflict-free (pattern
// correctness-verified R2/R3; swizzle stays within each 128B group so the
// DMA stays fully coalesced). Uniform weights from ws via scalar loads
// (overlap the DMA). MLP evaluated 2 steps at a time packed in v2f.
__global__ void __launch_bounds__(TPB) onenet_main(
    const float* __restrict__ X, float* __restrict__ ws)
{
    __shared__ float4 tile[TPB * 5];          // 20 KB staging -> 7 blocks/CU
    __shared__ float  red[TPB / 64][9];

    const int bid  = blockIdx.x;
    const int row  = bid >> 2;
    const int q    = bid & 3;
    const int tid  = threadIdx.x;
    const int lane = tid & 63;
    const int w    = tid >> 6;

    // ---- async staging: quarter-row (1024 steps, 20 KB) ----
    const float* Xq = X + ((size_t)row * NL + (size_t)q * QSTEP) * 5;
#pragma unroll
    for (int k = 0; k < 5; ++k) {
        int jbase = 320 * w + 64 * k;         // wave-uniform dest float4 idx
        int j     = jbase + lane;
        int sj    = j ^ ((j >> 3) & 7);       // involution: tile[i] = g[sw(i)]
        __builtin_amdgcn_global_load_lds(
            (const __attribute__((address_space(1))) void*)(Xq + 4 * (size_t)sj),
            (__attribute__((address_space(3))) void*)&tile[jbase],
            16, 0, 0);
    }

    // ---- uniform weights (wave-uniform -> scalar loads) during DMA ----
    float W1S[10], W1T[10], BASE[10];
    float VR1[10], VRC[10], VOC[10], VMH[10], VKH[10];
#pragma unroll
    for (int j = 0; j < 10; ++j) W1S[j] = ws[j];
#pragma unroll
    for (int j = 0; j < 10; ++j) W1T[j] = ws[10 + j];
#pragma unroll
    for (int j = 0; j < 10; ++j) {
        VR1[j] = ws[20 + 5 * j + 0];
        VRC[j] = ws[20 + 5 * j + 1];
        VOC[j] = ws[20 + 5 * j + 2];
        VMH[j] = ws[20 + 5 * j + 3];
        VKH[j] = ws[20 + 5 * j + 4];
    }
    const float A0 = ws[70], A1 = ws[71], A2 = ws[72], A3 = ws[73], A4 = ws[74];
    {
        const float* bp = ws + WS_BASE + row * 16;
#pragma unroll
        for (int j = 0; j < 10; ++j) BASE[j] = bp[j];
    }

    __syncthreads();                          // staging visible

    // ---- conflict-free LDS reads: this thread's 4 steps (20 floats) ----
    float f[20];
#pragma unroll
    for (int jj = 0; jj < 5; ++jj) {
        int widx = 5 * tid + jj;
        int sw   = widx ^ ((widx >> 3) & 7);
        *(float4*)&f[4 * jj] = tile[sw];
    }
    // t of the step after this thread's last
    float tn;
    {
        int wn  = 5 * ((tid + 1) & (TPB - 1));   // clamped for tid==255
        int swn = wn ^ ((wn >> 3) & 7);
        float tl = tile[swn].x;
        if (tid < TPB - 1)      tn = tl;
        else if (q == 3)        tn = f[15];      // dt=0 -> identity at step 4095
        else                    tn = Xq[QSTEP * 5];
    }

    v2f a = {1.f, 1.f}, b = {0.f, 0.f}, cS = {0.f, 0.f}, dS = {0.f, 0.f};
    v2f oaccv = {0.f, 0.f};
    float OCV0 = 0.f, I0 = 0.f;

#pragma unroll
    for (int ip = 0; ip < 2; ++ip) {          // two step-pairs: (0,1),(2,3)
        const int i0 = 2 * ip, i1 = 2 * ip + 1;
        v2f SSv = { f[5 * i0 + 4], f[5 * i1 + 4] };
        v2f Ttv = { f[5 * i0 + 2], f[5 * i1 + 2] };
        v2f Iv  = { f[5 * i0 + 1], f[5 * i1 + 1] };
        float tnx1 = (ip == 0) ? f[5 * i1 + 5] : tn;
        v2f dtv = { f[5 * i1 + 0] - f[5 * i0 + 0], tnx1 - f[5 * i1 + 0] };
        v2f invv = { fast_rcp(Iv.x), fast_rcp(Iv.y) };

        v2f tR1 = {A0, A0}, tRC = {A1, A1}, tOC = {A2, A2},
            tMH = {A3, A3}, tKH = {A4, A4};
#pragma unroll
        for (int j = 0; j < 10; ++j) {
            v2f pre = SSv * W1S[j] + Ttv * W1T[j] + BASE[j];
            v2f s   = pre * pre;
            v2f p   = s * SP_C3 + SP_C2;
            p = s * p + SP_C1;
            p = s * p + SP_C0;
            v2f lam = pre * 0.5f + p;          // softplus2(pre), poly approx
            tR1 += lam * VR1[j];
            tRC += lam * VRC[j];
            tOC += lam * VOC[j];
            tMH += lam * VMH[j];
            tKH += lam * VKH[j];
        }
        oaccv += tOC * invv;                   // negated at the end
        if (ip == 0) { OCV0 = tOC.x; I0 = Iv.x; }

        v2f g  = dtv * tKH * Iv;
        v2f hh = dtv * tRC;
        v2f bx = g * tMH;
        v2f by = hh * tR1 * Iv;

        {   // step i0 (S-accum with pre-step U, then apply T)
            v2f sv = {1.f + g.x, 1.f - hh.x};
            v2f bv = {bx.x, by.x};
            v2f iv = {invv.x, invv.x};
            cS = iv * a + cS;
            dS = iv * b + dS;
            b  = sv * b + bv;
            a  = sv * a;
        }
        {   // step i1
            v2f sv = {1.f + g.y, 1.f - hh.y};
            v2f bv = {bx.y, by.y};
            v2f iv = {invv.y, invv.y};
            cS = iv * a + cS;
            dS = iv * b + dS;
            b  = sv * b + bv;
            a  = sv * a;
        }
    }
    float oacc = -(oaccv.x + oaccv.y);

    // wave-level order-preserving tree reduce (L=self, R=lane+off)
#pragma unroll
    for (int off = 1; off < 64; off <<= 1) {
        v2f a2, b2, c2, d2;
        a2.x = __shfl_down(a.x, off);  a2.y = __shfl_down(a.y, off);
        b2.x = __shfl_down(b.x, off);  b2.y = __shfl_down(b.y, off);
        c2.x = __shfl_down(cS.x, off); c2.y = __shfl_down(cS.y, off);
        d2.x = __shfl_down(dS.x, off); d2.y = __shfl_down(dS.y, off);
        float o2 = __shfl_down(oacc, off);
        v2f nb = a2 * b + b2;
        v2f nc = c2 * a + cS;
        v2f nd = (dS + d2) + c2 * b;
        a = a2 * a; b = nb; cS = nc; dS = nd;
        oacc += o2;
    }

    if (lane == 0) {
        red[w][0] = a.x;  red[w][1] = a.y;
        red[w][2] = b.x;  red[w][3] = b.y;
        red[w][4] = cS.x; red[w][5] = cS.y;
        red[w][6] = dS.x; red[w][7] = dS.y;
        red[w][8] = oacc;
    }
    __syncthreads();

    if (tid == 0) {
#pragma unroll
        for (int k = 1; k < TPB / 64; ++k) {
            v2f ak, bk, ck, dk;
            ak.x = red[k][0]; ak.y = red[k][1];
            bk.x = red[k][2]; bk.y = red[k][3];
            ck.x = red[k][4]; ck.y = red[k][5];
            dk.x = red[k][6]; dk.y = red[k][7];
            v2f nb = ak * b + bk;
            v2f nc = ck * a + cS;
            v2f nd = (dS + dk) + ck * b;
            a = ak * a; b = nb; cS = nc; dS = nd;
            oacc += red[k][8];
        }
        float* pw = ws + WS_PART + (size_t)bid * 12;
        pw[0] = a.x;  pw[1] = b.x;  pw[2] = cS.x; pw[3] = dS.x;
        pw[4] = a.y;  pw[5] = b.y;  pw[6] = cS.y; pw[7] = dS.y;
        pw[8] = oacc;
        if (q == 0) { pw[9] = OCV0; pw[10] = I0; }
    }
}

// ---------------- kernel C: combine quarters + output ----------------
__global__ void __launch_bounds__(256) onenet_final(
    const float* __restrict__ ws, float* __restrict__ out)
{
    const int row = blockIdx.x * 256 + threadIdx.x;
    if (row >= NB) return;
    const float* p0 = ws + WS_PART + (size_t)row * 48;

    v2f a, b, cS, dS;
    a.x  = p0[0]; a.y  = p0[4];
    b.x  = p0[1]; b.y  = p0[5];
    cS.x = p0[2]; cS.y = p0[6];
    dS.x = p0[3]; dS.y = p0[7];
    float O = p0[8];
    float OCV0 = p0[9], I0 = p0[10];
#pragma unroll
    for (int k = 1; k < 4; ++k) {
        const float* pk = p0 + k * 12;
        v2f ak, bk, ck, dk;
        ak.x = pk[0]; ak.y = pk[4];
        bk.x = pk[1]; bk.y = pk[5];
        ck.x = pk[2]; ck.y = pk[6];
        dk.x = pk[3]; dk.y = pk[7];
        v2f nb = ak * b + bk;
        v2f nc = ck * a + cS;
        v2f nd = (dS + dk) + ck * b;
        a = ak * a; b = nb; cS = nc; dS = nd;
        O += pk[8];
    }
    float Rs  = ws[WS_BASE + row * 16 + 10];
    float U10 = -OCV0 - I0 * Rs;                 // U_H0 = 0
    float SH  = dS.x;                            // sum U_H/I
    float S1  = fmaf(cS.y, U10, dS.y);           // sum U_1/I
    out[row] = (O - SH - S1) * (1.0f / 4096.0f);
}

extern "C" void kernel_launch(void* const* d_in, const int* in_sizes, int n_in,
                              void* d_out, int out_size, void* d_ws, size_t ws_size,
                              hipStream_t stream) {
    const float* X   = (const float*)d_in[0];
    const float* SC  = (const float*)d_in[1];
    const float* pW1 = (const float*)d_in[2];
    const float* pb1 = (const float*)d_in[3];
    const float* pW2 = (const float*)d_in[4];
    const float* pb2 = (const float*)d_in[5];
    const float* rW1 = (const float*)d_in[6];
    const float* rb1 = (const float*)d_in[7];
    const float* rW2 = (const float*)d_in[8];
    const float* rb2 = (const float*)d_in[9];
    float* out = (float*)d_out;
    float* ws  = (float*)d_ws;

    onenet_prep<<<NB / 256, 256, 0, stream>>>(X, SC, pW1, pb1, pW2, pb2,
                                              rW1, rb1, rW2, rb2, ws);
    onenet_main<<<NB * 4, TPB, 0, stream>>>(X, ws);
    onenet_final<<<NB / 256, 256, 0, stream>>>(ws, out);
}